// Round 10
// baseline (779.256 us; speedup 1.0000x reference)
//
#include <hip/hip_runtime.h>

// ---------------------------------------------------------------------------
// Kernel A: i_x[t,b,n] = sum_k x[t,b,k] * w_in[k,n]
// Plain fp32 vector GEMM: M = T*B = 128000, K = 256, N = 256.  (~112 TF)
// ---------------------------------------------------------------------------
__global__ __launch_bounds__(256) void gemm_xw(const float* __restrict__ X,
                                               const float* __restrict__ W,
                                               float* __restrict__ Y,
                                               int M) {
    __shared__ float As[32][132];
    __shared__ float Bs[32][128];

    const int tid = threadIdx.x;
    const int mb = blockIdx.x >> 1;
    const int nb = blockIdx.x & 1;
    const int m0 = mb << 7;
    const int n0 = nb << 7;
    const int tr = (tid >> 4) << 3;
    const int tc = (tid & 15) << 3;

    float acc[8][8];
#pragma unroll
    for (int i = 0; i < 8; ++i)
#pragma unroll
        for (int j = 0; j < 8; ++j) acc[i][j] = 0.f;

    for (int kb = 0; kb < 256; kb += 32) {
#pragma unroll
        for (int i = 0; i < 4; ++i) {
            int f = tid + (i << 8);
            int row = f >> 3, kq = f & 7;
            float4 a = *(const float4*)(X + (size_t)(m0 + row) * 256 + kb + (kq << 2));
            As[(kq << 2) + 0][row] = a.x;
            As[(kq << 2) + 1][row] = a.y;
            As[(kq << 2) + 2][row] = a.z;
            As[(kq << 2) + 3][row] = a.w;
            int rowb = f >> 5, cq = f & 31;
            *(float4*)&Bs[rowb][cq << 2] =
                *(const float4*)(W + (size_t)(kb + rowb) * 256 + n0 + (cq << 2));
        }
        __syncthreads();
#pragma unroll
        for (int k = 0; k < 32; ++k) {
            float a[8], b[8];
            *(float4*)&a[0] = *(const float4*)&As[k][tr];
            *(float4*)&a[4] = *(const float4*)&As[k][tr + 4];
            *(float4*)&b[0] = *(const float4*)&Bs[k][tc];
            *(float4*)&b[4] = *(const float4*)&Bs[k][tc + 4];
#pragma unroll
            for (int i = 0; i < 8; ++i)
#pragma unroll
                for (int j = 0; j < 8; ++j)
                    acc[i][j] = fmaf(a[i], b[j], acc[i][j]);
        }
        __syncthreads();
    }
#pragma unroll
    for (int i = 0; i < 8; ++i) {
        float* yp = Y + (size_t)(m0 + tr + i) * 256 + n0 + tc;
        *(float4*)yp = make_float4(acc[i][0], acc[i][1], acc[i][2], acc[i][3]);
        *(float4*)(yp + 4) = make_float4(acc[i][4], acc[i][5], acc[i][6], acc[i][7]);
    }
}

// ---------------------------------------------------------------------------
// Kernel B: sequential scan, TWO SAMPLES PER WAVE interleaved. 64 blocks x
// 64 threads; wave owns samples 2w, 2w+1; lane owns neurons 4l..4l+3 of
// both. Two independent recurrences -> their instruction streams interleave
// and cover each other's dependency/branch/trans stalls (R6 ablation:
// single-wave step = ~800cy with only ~200cy of issue).
// R9 FIX vs R8: cT select polarity restored to R7 semantics —
//   h==0 (i_in==0)  -> arg = 0      -> g(0)  = G0
//   h==1            -> arg = t+1    -> g(t+1)= (1e-5 + (t+1)) + 1
// and L = log2(min(cT, cA)) exactly as R7 (g commutes with min: monotone).
// Memory: CHUNK=4 double-buffered ix loads, burst stores, fused-asm gather
// (load+vmcnt(0) in one asm -> no split hazard, counter left drained).
// i_x aliases zs: all loads of row r are issued before any store to row r.
// ---------------------------------------------------------------------------
__global__ __launch_bounds__(64) void lif_seq(const float* __restrict__ ix,
                                              const float* __restrict__ wrec,
                                              const float* __restrict__ z0,
                                              const float* __restrict__ v0,
                                              const float* __restrict__ t0,
                                              float* __restrict__ zs,
                                              float* __restrict__ vs,
                                              int T, int B) {
    const int b0 = blockIdx.x << 1;
    const int lane = threadIdx.x;
    const int nbase = lane << 2;
    const size_t sbA = (size_t)b0 * 256 + nbase;
    const size_t sbB = (size_t)(b0 + 1) * 256 + nbase;
    const size_t stride = (size_t)B * 256;

    float v[8], t[8];
    bool sp[8];
    {
        float4 a;
        a = *(const float4*)(v0 + sbA); v[0]=a.x; v[1]=a.y; v[2]=a.z; v[3]=a.w;
        a = *(const float4*)(v0 + sbB); v[4]=a.x; v[5]=a.y; v[6]=a.z; v[7]=a.w;
        a = *(const float4*)(t0 + sbA); t[0]=a.x; t[1]=a.y; t[2]=a.z; t[3]=a.w;
        a = *(const float4*)(t0 + sbB); t[4]=a.x; t[5]=a.y; t[6]=a.z; t[7]=a.w;
        a = *(const float4*)(z0 + sbA); sp[0]=a.x!=0.f; sp[1]=a.y!=0.f; sp[2]=a.z!=0.f; sp[3]=a.w!=0.f;
        a = *(const float4*)(z0 + sbB); sp[4]=a.x!=0.f; sp[5]=a.y!=0.f; sp[6]=a.z!=0.f; sp[7]=a.w!=0.f;
    }

    auto wload = [&](int row) -> float4 {
        const float* wp = wrec + ((size_t)row << 8) + nbase;
        float4 w4;
        asm volatile("global_load_dwordx4 %0, %1, off\n\ts_waitcnt vmcnt(0)"
                     : "=v"(w4) : "v"(wp) : "memory");
        return w4;
    };

    constexpr float G0 = 1e-5f + 1.0f;   // g(0), exact

    auto step2 = [&](float4 rA, float4 rB,
                     float4& zoA, float4& voA, float4& zoB, float4& voB) {
        unsigned long long mk[8];
#pragma unroll
        for (int e = 0; e < 8; ++e) mk[e] = __ballot(sp[e]);

        float rr[8] = {rA.x, rA.y, rA.z, rA.w, rB.x, rB.y, rB.z, rB.w};

        if (mk[0] | mk[1] | mk[2] | mk[3]) {       // sample A spikes
            float i0 = 0.f, i1 = 0.f, i2 = 0.f, i3 = 0.f;
            unsigned long long mm;
            mm = mk[0];
            while (mm) { int j = __builtin_ctzll(mm); mm &= mm - 1;
                float4 w = wload((j << 2) + 0);
                i0 += w.x; i1 += w.y; i2 += w.z; i3 += w.w; }
            mm = mk[1];
            while (mm) { int j = __builtin_ctzll(mm); mm &= mm - 1;
                float4 w = wload((j << 2) + 1);
                i0 += w.x; i1 += w.y; i2 += w.z; i3 += w.w; }
            mm = mk[2];
            while (mm) { int j = __builtin_ctzll(mm); mm &= mm - 1;
                float4 w = wload((j << 2) + 2);
                i0 += w.x; i1 += w.y; i2 += w.z; i3 += w.w; }
            mm = mk[3];
            while (mm) { int j = __builtin_ctzll(mm); mm &= mm - 1;
                float4 w = wload((j << 2) + 3);
                i0 += w.x; i1 += w.y; i2 += w.z; i3 += w.w; }
            rr[0] += i0; rr[1] += i1; rr[2] += i2; rr[3] += i3;
        }
        if (mk[4] | mk[5] | mk[6] | mk[7]) {       // sample B spikes
            float i0 = 0.f, i1 = 0.f, i2 = 0.f, i3 = 0.f;
            unsigned long long mm;
            mm = mk[4];
            while (mm) { int j = __builtin_ctzll(mm); mm &= mm - 1;
                float4 w = wload((j << 2) + 0);
                i0 += w.x; i1 += w.y; i2 += w.z; i3 += w.w; }
            mm = mk[5];
            while (mm) { int j = __builtin_ctzll(mm); mm &= mm - 1;
                float4 w = wload((j << 2) + 1);
                i0 += w.x; i1 += w.y; i2 += w.z; i3 += w.w; }
            mm = mk[6];
            while (mm) { int j = __builtin_ctzll(mm); mm &= mm - 1;
                float4 w = wload((j << 2) + 2);
                i0 += w.x; i1 += w.y; i2 += w.z; i3 += w.w; }
            mm = mk[7];
            while (mm) { int j = __builtin_ctzll(mm); mm &= mm - 1;
                float4 w = wload((j << 2) + 3);
                i0 += w.x; i1 += w.y; i2 += w.z; i3 += w.w; }
            rr[4] += i0; rr[5] += i1; rr[6] += i2; rr[7] += i3;
        }

        // ---- straight-line stage-wise math over 8 independent entries ----
        float tp1[8], cT[8], ntn[8], vc[8], E[8], cA[8], L[8], nv[8], zf[8];
        bool hz[8], spn[8];
#pragma unroll
        for (int e = 0; e < 8; ++e) hz[e] = (rr[e] == 0.f);
#pragma unroll
        for (int e = 0; e < 8; ++e) tp1[e] = t[e] + 1.f;
#pragma unroll
        for (int e = 0; e < 8; ++e) cT[e] = hz[e] ? G0 : ((1e-5f + tp1[e]) + 1.f);  // R7 polarity
#pragma unroll
        for (int e = 0; e < 8; ++e) ntn[e] = hz[e] ? tp1[e] : 0.f;
#pragma unroll
        for (int e = 0; e < 8; ++e) vc[e] = fmaxf(sp[e] ? 0.f : v[e], -1.f);
#pragma unroll
        for (int e = 0; e < 8; ++e) E[e] = __builtin_amdgcn_exp2f(fabsf(vc[e]));
#pragma unroll
        for (int e = 0; e < 8; ++e) cA[e] = (1e-5f + (E[e] - 1.f)) + 1.f;
#pragma unroll
        for (int e = 0; e < 8; ++e) L[e] = __builtin_amdgcn_logf(fminf(cT[e], cA[e]));
#pragma unroll
        for (int e = 0; e < 8; ++e) {
            float Ls = copysignf(L[e], vc[e]);
            float nvp = (vc[e] == 0.f) ? vc[e] : (vc[e] - Ls);
            nv[e] = nvp + rr[e];
        }
#pragma unroll
        for (int e = 0; e < 8; ++e) spn[e] = (nv[e] > 0.5f);
#pragma unroll
        for (int e = 0; e < 8; ++e) zf[e] = spn[e] ? 1.f : 0.f;
#pragma unroll
        for (int e = 0; e < 8; ++e) { v[e] = nv[e]; t[e] = ntn[e]; sp[e] = spn[e]; }

        zoA = make_float4(zf[0], zf[1], zf[2], zf[3]);
        voA = make_float4(nv[0], nv[1], nv[2], nv[3]);
        zoB = make_float4(zf[4], zf[5], zf[6], zf[7]);
        voB = make_float4(nv[4], nv[5], nv[6], nv[7]);
    };

    float4 iA0[4], iB0[4], iA1[4], iB1[4];
    float4 zoA[4], voA[4], zoB[4], voB[4];

    auto loadChunk = [&](float4 (&bA)[4], float4 (&bB)[4], int c0) {
#pragma unroll
        for (int u = 0; u < 4; ++u) {
            int r = c0 + u;
            r = (r < T) ? r : T - 1;
            bA[u] = *(const float4*)(ix + (size_t)r * stride + sbA);
            bB[u] = *(const float4*)(ix + (size_t)r * stride + sbB);
        }
    };

    auto runChunk = [&](float4 (&bA)[4], float4 (&bB)[4], int c0) {
#pragma unroll
        for (int u = 0; u < 4; ++u)
            step2(bA[u], bB[u], zoA[u], voA[u], zoB[u], voB[u]);
#pragma unroll
        for (int u = 0; u < 4; ++u) {
            size_t o = (size_t)(c0 + u) * stride;
            *(float4*)(zs + o + sbA) = zoA[u];
            *(float4*)(vs + o + sbA) = voA[u];
            *(float4*)(zs + o + sbB) = zoB[u];
            *(float4*)(vs + o + sbB) = voB[u];
        }
    };

    loadChunk(iA0, iB0, 0);
    int c = 0;
    while (c + 8 <= T) {
        loadChunk(iA1, iB1, c + 4);
        runChunk(iA0, iB0, c);
        loadChunk(iA0, iB0, c + 8);   // clamped prefetch at tail (dummy rows)
        runChunk(iA1, iB1, c + 4);
        c += 8;
    }
    if (c + 4 <= T) {                 // leftover full chunk (iA0/iB0 hold it)
        runChunk(iA0, iB0, c);
        c += 4;
    }
    for (int ts = c; ts < T; ++ts) {  // scalar tail
        float4 rA = *(const float4*)(ix + (size_t)ts * stride + sbA);
        float4 rB = *(const float4*)(ix + (size_t)ts * stride + sbB);
        float4 za, va, zb, vb;
        step2(rA, rB, za, va, zb, vb);
        size_t o = (size_t)ts * stride;
        *(float4*)(zs + o + sbA) = za;
        *(float4*)(vs + o + sbA) = va;
        *(float4*)(zs + o + sbB) = zb;
        *(float4*)(vs + o + sbB) = vb;
    }
}

extern "C" void kernel_launch(void* const* d_in, const int* in_sizes, int n_in,
                              void* d_out, int out_size, void* d_ws, size_t ws_size,
                              hipStream_t stream) {
    const float* x    = (const float*)d_in[0];
    const float* z0   = (const float*)d_in[1];
    const float* v0   = (const float*)d_in[2];
    const float* t0   = (const float*)d_in[3];
    const float* w_in = (const float*)d_in[4];
    const float* wrec = (const float*)d_in[5];

    const int n_rec = 256;
    const int B = in_sizes[1] / n_rec;          // 128 (even)
    const int nin = in_sizes[4] / n_rec;        // 256
    const int T = in_sizes[0] / (B * nin);      // 1000
    const int M = T * B;                        // 128000

    float* zs = (float*)d_out;
    float* vs = zs + (size_t)T * B * n_rec;
    float* ixbuf = zs;  // stage x@w_in into the zs region (read-before-write in lif_seq)

    gemm_xw<<<dim3((M / 128) * 2), dim3(256), 0, stream>>>(x, w_in, ixbuf, M);
    lif_seq<<<dim3(B >> 1), dim3(64), 0, stream>>>(ixbuf, wrec, z0, v0, t0, zs, vs, T, B);
}

// Round 12
// 498.945 us; speedup vs baseline: 1.5618x; 1.5618x over previous
//
#include <hip/hip_runtime.h>

// ---------------------------------------------------------------------------
// Kernel A: i_x[t,b,n] = sum_k x[t,b,k] * w_in[k,n]
// Plain fp32 vector GEMM: M = T*B = 128000, K = 256, N = 256.  (~112 TF)
// ---------------------------------------------------------------------------
__global__ __launch_bounds__(256) void gemm_xw(const float* __restrict__ X,
                                               const float* __restrict__ W,
                                               float* __restrict__ Y,
                                               int M) {
    __shared__ float As[32][132];
    __shared__ float Bs[32][128];

    const int tid = threadIdx.x;
    const int mb = blockIdx.x >> 1;
    const int nb = blockIdx.x & 1;
    const int m0 = mb << 7;
    const int n0 = nb << 7;
    const int tr = (tid >> 4) << 3;
    const int tc = (tid & 15) << 3;

    float acc[8][8];
#pragma unroll
    for (int i = 0; i < 8; ++i)
#pragma unroll
        for (int j = 0; j < 8; ++j) acc[i][j] = 0.f;

    for (int kb = 0; kb < 256; kb += 32) {
#pragma unroll
        for (int i = 0; i < 4; ++i) {
            int f = tid + (i << 8);
            int row = f >> 3, kq = f & 7;
            float4 a = *(const float4*)(X + (size_t)(m0 + row) * 256 + kb + (kq << 2));
            As[(kq << 2) + 0][row] = a.x;
            As[(kq << 2) + 1][row] = a.y;
            As[(kq << 2) + 2][row] = a.z;
            As[(kq << 2) + 3][row] = a.w;
            int rowb = f >> 5, cq = f & 31;
            *(float4*)&Bs[rowb][cq << 2] =
                *(const float4*)(W + (size_t)(kb + rowb) * 256 + n0 + (cq << 2));
        }
        __syncthreads();
#pragma unroll
        for (int k = 0; k < 32; ++k) {
            float a[8], b[8];
            *(float4*)&a[0] = *(const float4*)&As[k][tr];
            *(float4*)&a[4] = *(const float4*)&As[k][tr + 4];
            *(float4*)&b[0] = *(const float4*)&Bs[k][tc];
            *(float4*)&b[4] = *(const float4*)&Bs[k][tc + 4];
#pragma unroll
            for (int i = 0; i < 8; ++i)
#pragma unroll
                for (int j = 0; j < 8; ++j)
                    acc[i][j] = fmaf(a[i], b[j], acc[i][j]);
        }
        __syncthreads();
    }
#pragma unroll
    for (int i = 0; i < 8; ++i) {
        float* yp = Y + (size_t)(m0 + tr + i) * 256 + n0 + tc;
        *(float4*)yp = make_float4(acc[i][0], acc[i][1], acc[i][2], acc[i][3]);
        *(float4*)(yp + 4) = make_float4(acc[i][4], acc[i][5], acc[i][6], acc[i][7]);
    }
}

// ---------------------------------------------------------------------------
// Kernel B: sequential scan, FOUR WAVES per sample (256 threads, 1 neuron
// per lane). Per-wave issue-bound recurrence (R9) -> minimize instructions
// per wave (~25-30 VALU/step/wave vs ~200 in the 1-wave kernel).
// Cross-wave spike exchange: ballot -> lane0 ds_write -> ONE barrier ->
// broadcast ds_read, double-buffered slots (R1-proven race-free).
// R11 FIX vs R10: masks consumed DIRECTLY from the LDS broadcast reads
// (wave-uniform values), exactly as R1/R7 did. The readfirstlane SGPR-pin
// is deleted — its low-word path sign-extended int->u64 and set the high
// 32 mask bits whenever lane 31 spiked (R10's absmax=1.0).
// SPECULATION: leak/transcendental chain depends only on (v,t,sp,rr), so
// it's computed inside the LDS-read latency shadow; common path (no spike
// anywhere, ~75% of steps) is bit-exact since ir==0 => i_in == rr. Rare
// spike steps gather w_rec rows (coalesced scalar loads) and recompute the
// i_in-dependent tail with identical formulas.
// Memory: CHUNK=4 dbuf ix loads + burst stores. i_x aliases zs: each
// thread touches only its own element; loads of row r precede stores to r
// in program order.
// ---------------------------------------------------------------------------
__global__ __launch_bounds__(256) void lif_seq4(const float* __restrict__ ix,
                                                const float* __restrict__ wrec,
                                                const float* __restrict__ z0,
                                                const float* __restrict__ v0,
                                                const float* __restrict__ t0,
                                                float* __restrict__ zs,
                                                float* __restrict__ vs,
                                                int T, int B) {
    const int b = blockIdx.x;
    const int tid = threadIdx.x;        // neuron 0..255
    const int wv = tid >> 6;            // wave 0..3
    const int lane = tid & 63;
    const size_t sb = (size_t)b * 256 + tid;
    const size_t stride = (size_t)B * 256;

    __shared__ unsigned long long smask[2][4];

    float v = v0[sb];
    float t = t0[sb];
    bool sp = (z0[sb] != 0.f);
    int p = 0;

    const float* ixp = ix + sb;

    constexpr float G0 = 1e-5f + 1.0f;   // g(0), exact

    auto step = [&](float rr, float& zo_, float& vo_) {
        // ---- publish my wave's spike mask, fetch all 4 ----
        unsigned long long mk = __ballot(sp);
        if (lane == 0) smask[p][wv] = mk;
        __syncthreads();
        unsigned long long m0 = smask[p][0];
        unsigned long long m1 = smask[p][1];
        unsigned long long m2 = smask[p][2];
        unsigned long long m3 = smask[p][3];
        p ^= 1;

        // ---- speculative leak math (independent of masks; fills the
        //      LDS-read latency shadow). ir==0 => i_in == rr bitwise. ----
        float vc = fmaxf(sp ? 0.f : v, -1.f);
        float E  = __builtin_amdgcn_exp2f(fabsf(vc));
        float cA = (1e-5f + (E - 1.f)) + 1.f;
        float tp1 = t + 1.f;
        bool hz = (rr == 0.f);
        float cT = hz ? G0 : ((1e-5f + tp1) + 1.f);
        float L  = __builtin_amdgcn_logf(fminf(cT, cA));
        float Ls = copysignf(L, vc);
        float nvp = (vc == 0.f) ? vc : (vc - Ls);
        float nv  = nvp + rr;
        float ntn = hz ? tp1 : 0.f;

        // ---- consume masks (block-uniform branch) ----
        if ((m0 | m1 | m2 | m3) != 0ull) {
            // rare: gather recurrent input, redo the i_in-dependent tail
            float ir = 0.f;
            unsigned long long mm;
            mm = m0;
            while (mm) { int j = __builtin_ctzll(mm); mm &= mm - 1;
                ir += wrec[((size_t)j << 8) + tid]; }
            mm = m1;
            while (mm) { int j = __builtin_ctzll(mm); mm &= mm - 1;
                ir += wrec[((size_t)(64 + j) << 8) + tid]; }
            mm = m2;
            while (mm) { int j = __builtin_ctzll(mm); mm &= mm - 1;
                ir += wrec[((size_t)(128 + j) << 8) + tid]; }
            mm = m3;
            while (mm) { int j = __builtin_ctzll(mm); mm &= mm - 1;
                ir += wrec[((size_t)(192 + j) << 8) + tid]; }

            float i_in = rr + ir;
            bool hz2 = (i_in == 0.f);
            float cT2 = hz2 ? G0 : ((1e-5f + tp1) + 1.f);
            float L2  = __builtin_amdgcn_logf(fminf(cT2, cA));
            float Ls2 = copysignf(L2, vc);
            float nvp2 = (vc == 0.f) ? vc : (vc - Ls2);
            nv  = nvp2 + i_in;
            ntn = hz2 ? tp1 : 0.f;
        }

        sp = (nv > 0.5f);
        v = nv;
        t = ntn;
        zo_ = sp ? 1.f : 0.f;
        vo_ = nv;
    };

    float iA[4], iB[4], zo[4], vo[4];

    auto loadChunk = [&](float (&bf)[4], int c0) {
#pragma unroll
        for (int u = 0; u < 4; ++u) {
            int r = c0 + u;
            r = (r < T) ? r : T - 1;       // clamped dummy at tail, never consumed
            bf[u] = ixp[(size_t)r * stride];
        }
    };

    auto runChunk = [&](float (&bf)[4], int c0) {
#pragma unroll
        for (int u = 0; u < 4; ++u) step(bf[u], zo[u], vo[u]);
        // burst store (coalesced scalar stores; source regs reused a full
        // chunk later so hazard waits hit retired stores)
#pragma unroll
        for (int u = 0; u < 4; ++u) {
            size_t o = (size_t)(c0 + u) * stride + sb;
            zs[o] = zo[u];
            vs[o] = vo[u];
        }
    };

    loadChunk(iA, 0);
    int c = 0;
    while (c + 8 <= T) {
        loadChunk(iB, c + 4);
        runChunk(iA, c);
        loadChunk(iA, c + 8);
        runChunk(iB, c + 4);
        c += 8;
    }
    if (c + 4 <= T) {                     // leftover full chunk
        runChunk(iA, c);
        c += 4;
    }
    for (int ts = c; ts < T; ++ts) {      // scalar tail
        float r = ixp[(size_t)ts * stride];
        float zz, vv;
        step(r, zz, vv);
        size_t o = (size_t)ts * stride + sb;
        zs[o] = zz;
        vs[o] = vv;
    }
}

extern "C" void kernel_launch(void* const* d_in, const int* in_sizes, int n_in,
                              void* d_out, int out_size, void* d_ws, size_t ws_size,
                              hipStream_t stream) {
    const float* x    = (const float*)d_in[0];
    const float* z0   = (const float*)d_in[1];
    const float* v0   = (const float*)d_in[2];
    const float* t0   = (const float*)d_in[3];
    const float* w_in = (const float*)d_in[4];
    const float* wrec = (const float*)d_in[5];

    const int n_rec = 256;
    const int B = in_sizes[1] / n_rec;          // 128
    const int nin = in_sizes[4] / n_rec;        // 256
    const int T = in_sizes[0] / (B * nin);      // 1000
    const int M = T * B;                        // 128000

    float* zs = (float*)d_out;
    float* vs = zs + (size_t)T * B * n_rec;
    float* ixbuf = zs;  // stage x@w_in into the zs region (read-before-write in lif_seq4)

    gemm_xw<<<dim3((M / 128) * 2), dim3(256), 0, stream>>>(x, w_in, ixbuf, M);
    lif_seq4<<<dim3(B), dim3(256), 0, stream>>>(ixbuf, wrec, z0, v0, t0, zs, vs, T, B);
}